// Round 14
// baseline (1128.068 us; speedup 1.0000x reference)
//
#include <hip/hip_runtime.h>
#include <hip/hip_bf16.h>

#define RES 64
#define WIDTH 32
#define MODES 8
#define R3 262144            // 64^3
#define TWO_PI_OVER_64 0.09817477042468103f

__device__ __forceinline__ float geluf(float x) {
    // jax.nn.gelu approximate=True: x * sigmoid(1.595769...*(x+0.044715x^3))
    float g = 1.5957691216057308f * (x + 0.044715f * x * x * x);
    return x * __builtin_amdgcn_rcpf(1.0f + __expf(-g));
}

// Compile-time twiddle table: constexpr Taylor cos/sin so the fully-unrolled z-DFT
// folds every twiddle to a literal. ONLY safe with COMPILE-TIME indices: runtime
// indices lower to v_cndmask select-trees (r11: 2x VALU regression). [journal rule]
constexpr double tcos_(double x) {
    double r = 1.0, term = 1.0;
    for (int i = 1; i <= 12; i++) { term *= -x * x / ((2.0 * i - 1.0) * (2.0 * i)); r += term; }
    return r;
}
constexpr double tsin_(double x) {
    double r = x, term = x;
    for (int i = 1; i <= 12; i++) { term *= -x * x / ((2.0 * i) * (2.0 * i + 1.0)); r += term; }
    return r;
}
struct Tw64 { float c[64]; float s[64]; };
constexpr Tw64 mkTw() {
    Tw64 t{};
    const double th = 6.283185307179586476925286766559 / 64.0;
    for (int i = 0; i < 64; i++) {
        double a = th * (i <= 32 ? i : i - 64);   // reduce to [-pi, pi] for Taylor
        t.c[i] = (float)tcos_(a);
        t.s[i] = (float)tsin_(a);
    }
    return t;
}
constexpr Tw64 TWT = mkTw();

// ---------------- K0: fc0 pointwise (3 -> 32) ----------------
__global__ void k_fc0(const float* __restrict__ u, const float* __restrict__ w,
                      const float* __restrict__ bias, float* __restrict__ X) {
    __shared__ float ws[96];
    __shared__ float bs[32];
    int t = threadIdx.x;
    if (t < 96) ws[t] = w[t];
    if (t < 32) bs[t] = bias[t];
    __syncthreads();
    size_t s = (size_t)blockIdx.x * 256 + t;     // over B*R3 = 1048576
    int b = (int)(s >> 18);
    size_t p = s & (R3 - 1);
    const float* ub = u + (size_t)b * 3 * R3;
    float u0 = ub[p], u1 = ub[R3 + p], u2 = ub[2 * R3 + p];
    float* xb = X + (size_t)b * 32 * R3;
    #pragma unroll
    for (int o = 0; o < 32; o++) {
        xb[(size_t)o * R3 + p] = bs[o] + u0 * ws[o] + u1 * ws[32 + o] + u2 * ws[64 + o];
    }
}

// ---------------- K1: fused forward DFT over z (64->8) and y (64->16 bins) ----------------
// One row per LANE, direct global b128 reads, literal twiddles (compile-time TWT indices)
// + z->z+32 even/odd fold. Block = 4 (b,c,x) planes (one per wave). 2048 blocks.
// r13 change: S2 stored in FUSED-CHAIN layout [b][jy][kz][c][x] so k_modes reads are
// contiguous 16 KB panels (index permutation only; values identical).
__global__ void __launch_bounds__(256, 6)
k_fwd_zy(const float* __restrict__ X, float2* __restrict__ S2) {
    int t = threadIdx.x;
    int q = t >> 6, y = t & 63;                  // wave q handles plane bcx0+q, lane = y row
    int bcx0 = blockIdx.x * 4;
    __shared__ float2 zt[4][8][66];              // [plane][kz][y], padded 64->66 (conflict-free)
    __shared__ float2 tw[64];
    if (t < 64) { float s, c; __sincosf(TWO_PI_OVER_64 * t, &s, &c); tw[t] = make_float2(c, s); }

    // ---- stage 1: z-DFT (64 -> 8 bins), one row per thread ----
    const float* row = X + (size_t)(bcx0 + q) * 4096 + (size_t)y * 64;
    float re[8], im[8];
    #pragma unroll
    for (int k = 0; k < 8; k++) { re[k] = 0.f; im[k] = 0.f; }
    #pragma unroll
    for (int zb = 0; zb < 8; zb++) {
        float xa[4], xb4[4];
        *(float4*)xa  = *(const float4*)(row + zb * 4);
        *(float4*)xb4 = *(const float4*)(row + zb * 4 + 32);
        #pragma unroll
        for (int j = 0; j < 4; j++) {
            int z = zb * 4 + j;                  // z in [0,32)
            float sv = xa[j] + xb4[j];           // even-k fold: x[z] + x[z+32]
            float dv = xa[j] - xb4[j];           // odd-k fold:  x[z] - x[z+32]
            #pragma unroll
            for (int k = 0; k < 8; k++) {
                float v = (k & 1) ? dv : sv;
                re[k] += v * TWT.c[(k * z) & 63];   // literal constants after unroll
                im[k] -= v * TWT.s[(k * z) & 63];
            }
        }
    }
    #pragma unroll
    for (int k = 0; k < 8; k++) zt[q][k][y] = make_float2(re[k], im[k]);
    __syncthreads();

    // ---- stage 2: y-DFT (64 -> 16 bins), 2 outputs per thread ----
    int l = t & 63;
    int jy = l >> 2, kp = l & 3;
    int f = jy < 8 ? jy : 48 + jy;
    int k0 = kp * 2;
    float re0 = 0.f, im0 = 0.f, re1 = 0.f, im1 = 0.f;
    #pragma unroll 8
    for (int yy = 0; yy < 64; yy++) {
        float2 w = tw[(f * yy) & 63];
        float2 v0 = zt[q][k0][yy];
        float2 v1 = zt[q][k0 + 1][yy];
        re0 += v0.x * w.x + v0.y * w.y;          // * conj(w)
        im0 += v0.y * w.x - v0.x * w.y;
        re1 += v1.x * w.x + v1.y * w.y;
        im1 += v1.y * w.x - v1.x * w.y;
    }
    int plane = bcx0 + q;
    int bc = plane >> 6, xx = plane & 63;
    int bb = bc >> 5, cc = bc & 31;
    // S2 layout [b][jy][kz][c][x]:
    float2* dst0 = S2 + ((size_t)((bb * 16 + jy) * 8 + k0)) * 2048 + cc * 64 + xx;
    dst0[0]    = make_float2(re0, im0);
    dst0[2048] = make_float2(re1, im1);
}

// ---------------- K2: fused mode-space chain: fwd-x DFT + spectral mul + inv-x DFT ----------
// Replaces k_fwd_x + k_specmul + k_inv_x (r13): block per (b, jy, kz) = 512 blocks.
// S2 panel [c][x] (16 KB) -> LDS; x-DFT (64->16 bins) -> Fs; spectral multiply over c
// (weights streamed from global; 32 blocks share each weight line via b/kz -> L2) -> Gs;
// inverse x-DFT (16 -> 64) -> S5 (layout unchanged, K5 untouched).
// Summation orders (x asc, i asc, jx asc) identical to the three originals -> bit-identical.
__global__ void __launch_bounds__(256, 2)
k_modes(const float2* __restrict__ S2, const float* __restrict__ spec_w,
        float2* __restrict__ S5, int layer) {
    int blk = blockIdx.x;                 // = (b*16 + jy)*8 + kz
    int kz = blk & 7, jy = (blk >> 3) & 15, b = blk >> 7;
    int t = threadIdx.x;
    __shared__ float2 As[2048];           // [c][x]   16 KB
    __shared__ float2 Fs[512];            // [c][jx]   4 KB
    __shared__ float2 Gs[512];            // [o][jx]   4 KB
    __shared__ float2 tw[64];
    if (t < 64) { float s, c; __sincosf(TWO_PI_OVER_64 * t, &s, &c); tw[t] = make_float2(c, s); }
    const float2* s2b = S2 + (size_t)blk * 2048;
    #pragma unroll
    for (int i = 0; i < 4; i++)
        ((float4*)As)[t + 256 * i] = ((const float4*)s2b)[t + 256 * i];
    __syncthreads();
    // fwd_x: Fs[c*16+jx] = sum_x As[c][x] * conj(tw[f*x])
    #pragma unroll
    for (int i2 = 0; i2 < 2; i2++) {
        int e = t + 256 * i2;
        int c = e >> 4, jx = e & 15;
        int f = jx < 8 ? jx : 48 + jx;
        const float2* arow = As + c * 64;
        float re = 0.f, im = 0.f;
        for (int x = 0; x < 64; x++) {
            float2 v = arow[x];
            float2 w = tw[(f * x) & 63];
            re += v.x * w.x + v.y * w.y;
            im += v.y * w.x - v.x * w.y;
        }
        Fs[e] = make_float2(re, im);
    }
    __syncthreads();
    // specmul: Gs[o*16+jx] = sum_i Fs[i*16+jx] * W[corner][i][o][jx&7][jy&7][kz]
    #pragma unroll
    for (int i2 = 0; i2 < 2; i2++) {
        int e = t + 256 * i2;
        int o = e >> 4, jx = e & 15;
        int corner = (jx >= 8 ? 1 : 0) + (jy >= 8 ? 2 : 0);
        const float* wb = spec_w + (size_t)layer * 4194304 + (size_t)corner * 1048576
                        + (size_t)o * 1024 + (jx & 7) * 128 + (jy & 7) * 16 + kz * 2;
        float re = 0.f, im = 0.f;
        #pragma unroll 8
        for (int i = 0; i < 32; i++) {
            float2 a = Fs[i * 16 + jx];
            const float* wp = wb + (size_t)i * 32768;
            float wr = wp[0], wi = wp[1];
            re += a.x * wr - a.y * wi;
            im += a.x * wi + a.y * wr;
        }
        Gs[e] = make_float2(re, im);
    }
    __syncthreads();
    // inv_x: S5[((b*32+o)*64+x)*128 + jy*8 + kz] = sum_jx Gs[o*16+jx] * tw[+f*x]
    #pragma unroll
    for (int i2 = 0; i2 < 8; i2++) {
        int e = t + 256 * i2;
        int o = e >> 6, x = e & 63;       // o is wave-uniform -> Gs reads are broadcasts
        float re = 0.f, im = 0.f;
        #pragma unroll
        for (int jx = 0; jx < 16; jx++) {
            int f = jx < 8 ? jx : 48 + jx;
            float2 v = Gs[o * 16 + jx];
            float2 w = tw[(f * x) & 63];
            re += v.x * w.x - v.y * w.y;   // e^{+i theta}
            im += v.x * w.y + v.y * w.x;
        }
        S5[((size_t)(b * 32 + o) * 64 + x) * 128 + jy * 8 + kz] = make_float2(re, im);
    }
}

// ---------------- K5: fused inverse-y + inverse-z DFT + pointwise + add + gelu (IN-PLACE on X) ----
// v8 form (verified 111 us/dispatch; r12/r13 confirmed local optimum — do not diet further).
__global__ void __launch_bounds__(256, 3)
k_inv_yz_pw(const float2* __restrict__ S5, const float* __restrict__ w_pw,
            const float* __restrict__ b_pw, float* __restrict__ X,
            int layer, int do_gelu) {
    int blk = blockIdx.x;
    int yg = blk & 7, x = (blk >> 3) & 63, b = blk >> 9;
    int t = threadIdx.x;
    __shared__ float2 s5s[32 * 132];   // [o][jy*8+k], padded rows  33792 B
    __shared__ float2 st[256];         // [o][k]        2 KB
    __shared__ float xt[2048];         // [c][z]        8 KB
    __shared__ float2 tw[64];
    if (t < 64) { float s, c; __sincosf(TWO_PI_OVER_64 * t, &s, &c); tw[t] = make_float2(c, s); }
    // stage s5s: coalesced float4 loads (per o: 128 contiguous float2), padded store
    #pragma unroll
    for (int i = 0; i < 8; i++) {
        int f4 = t + 256 * i;          // [0,2048): o*64 + j4
        int o = f4 >> 6, j4 = f4 & 63;
        float4 v = ((const float4*)(S5 + ((size_t)(b * 32 + o) * 64 + x) * 128))[j4];
        *(float4*)(&s5s[o * 132 + j4 * 2]) = v;
    }
    size_t base0 = (size_t)b * 8388608 + (size_t)(x * 64 + yg * 8) * 64;
    // prologue: prefetch X column for yi = 0 into registers (overlaps s5s staging)
    float xr0, xr1, xr2, xr3, xr4, xr5, xr6, xr7;
    {
        const float* xp = X + base0 + (t & 63);
        int c0 = t >> 6;               // c = c0 + 4*i for i-th load
        xr0 = xp[(size_t)(c0 +  0) * R3];
        xr1 = xp[(size_t)(c0 +  4) * R3];
        xr2 = xp[(size_t)(c0 +  8) * R3];
        xr3 = xp[(size_t)(c0 + 12) * R3];
        xr4 = xp[(size_t)(c0 + 16) * R3];
        xr5 = xp[(size_t)(c0 + 20) * R3];
        xr6 = xp[(size_t)(c0 + 24) * R3];
        xr7 = xp[(size_t)(c0 + 28) * R3];
    }
    __syncthreads();
    int z = t & 63, og = t >> 6;       // og is wave-uniform (wave = 64 lanes)
    int og8 = og * 8;
    int og8u = __builtin_amdgcn_readfirstlane(og8);   // SGPR: uniform weight row base
    const float* wl = w_pw + layer * 1024 + og8u;     // uniform -> s_load
    const float* bl = b_pw + layer * 32 + og8u;       // uniform -> s_load
    float bt0 = bl[0], bt1 = bl[1], bt2 = bl[2], bt3 = bl[3];
    float bt4 = bl[4], bt5 = bl[5], bt6 = bl[6], bt7 = bl[7];
    // named z-twiddle registers (k=0 twiddle is (1,0): handled inline)
    float2 tz1 = tw[z];
    float2 tz2 = tw[(2 * z) & 63];
    float2 tz3 = tw[(3 * z) & 63];
    float2 tz4 = tw[(4 * z) & 63];
    float2 tz5 = tw[(5 * z) & 63];
    float2 tz6 = tw[(6 * z) & 63];
    float2 tz7 = tw[(7 * z) & 63];
    const float inv_n = 1.0f / 262144.0f;
    for (int yi = 0; yi < 8; yi++) {
        int y = yg * 8 + yi;
        size_t base = base0 + (size_t)yi * 64;
        // stage B: commit prefetched registers to xt (xt[c*64 + z], c = (t>>6) + 4*i)
        {
            int e = t;                  // e + 256*i == (c0+4i)*64 + z
            xt[e +    0] = xr0; xt[e +  256] = xr1; xt[e +  512] = xr2; xt[e +  768] = xr3;
            xt[e + 1024] = xr4; xt[e + 1280] = xr5; xt[e + 1536] = xr6; xt[e + 1792] = xr7;
        }
        // stage A: inverse-y for this y -> st[o][k]; padded s5s rows (conflict-free)
        {
            int o = t >> 3, k = t & 7;
            float re = 0.f, im = 0.f;
            #pragma unroll
            for (int jy = 0; jy < 16; jy++) {
                int f = jy < 8 ? jy : 48 + jy;
                float2 v = s5s[o * 132 + jy * 8 + k];
                float2 w = tw[(f * y) & 63];
                re += v.x * w.x - v.y * w.y;   // e^{+i theta}
                im += v.x * w.y + v.y * w.x;
            }
            st[t] = make_float2(re, im);
        }
        __syncthreads();
        // T14 prefetch: issue yi+1's X loads now; latency hides under stage C
        if (yi < 7) {
            const float* xp = X + base + 64 + (t & 63);
            int c0 = t >> 6;
            xr0 = xp[(size_t)(c0 +  0) * R3];
            xr1 = xp[(size_t)(c0 +  4) * R3];
            xr2 = xp[(size_t)(c0 +  8) * R3];
            xr3 = xp[(size_t)(c0 + 12) * R3];
            xr4 = xp[(size_t)(c0 + 16) * R3];
            xr5 = xp[(size_t)(c0 + 20) * R3];
            xr6 = xp[(size_t)(c0 + 24) * R3];
            xr7 = xp[(size_t)(c0 + 28) * R3];
        }
        // stage C init: inverse-z (pocketfft c2r: Re of k=0, 2x k=1..7); st reads are
        // wave-uniform b64 broadcasts (og wave-uniform). All values named scalars.
#define INVZ_S(o) (st[(o) * 8 + 0].x \
        + 2.f * (st[(o) * 8 + 1].x * tz1.x - st[(o) * 8 + 1].y * tz1.y) \
        + 2.f * (st[(o) * 8 + 2].x * tz2.x - st[(o) * 8 + 2].y * tz2.y) \
        + 2.f * (st[(o) * 8 + 3].x * tz3.x - st[(o) * 8 + 3].y * tz3.y) \
        + 2.f * (st[(o) * 8 + 4].x * tz4.x - st[(o) * 8 + 4].y * tz4.y) \
        + 2.f * (st[(o) * 8 + 5].x * tz5.x - st[(o) * 8 + 5].y * tz5.y) \
        + 2.f * (st[(o) * 8 + 6].x * tz6.x - st[(o) * 8 + 6].y * tz6.y) \
        + 2.f * (st[(o) * 8 + 7].x * tz7.x - st[(o) * 8 + 7].y * tz7.y))
        float acc0 = bt0 + INVZ_S(og8 + 0) * inv_n;
        float acc1 = bt1 + INVZ_S(og8 + 1) * inv_n;
        float acc2 = bt2 + INVZ_S(og8 + 2) * inv_n;
        float acc3 = bt3 + INVZ_S(og8 + 3) * inv_n;
        float acc4 = bt4 + INVZ_S(og8 + 4) * inv_n;
        float acc5 = bt5 + INVZ_S(og8 + 5) * inv_n;
        float acc6 = bt6 + INVZ_S(og8 + 6) * inv_n;
        float acc7 = bt7 + INVZ_S(og8 + 7) * inv_n;
#undef INVZ_S
        // stage C main: c-outer pointwise; xt once per c; weights via SMEM (s_load).
        #pragma unroll 4
        for (int c = 0; c < 32; c++) {
            float xc = xt[c * 64 + z];
            const float* wr = wl + c * 32;                 // uniform: s_load_dwordx8
            float w0 = wr[0], w1 = wr[1], w2 = wr[2], w3 = wr[3];
            float w4 = wr[4], w5 = wr[5], w6 = wr[6], w7 = wr[7];
            acc0 += xc * w0; acc1 += xc * w1; acc2 += xc * w2; acc3 += xc * w3;
            acc4 += xc * w4; acc5 += xc * w5; acc6 += xc * w6; acc7 += xc * w7;
        }
        __syncthreads();   // all st/xt reads done before next iteration overwrites
        float r;
        r = do_gelu ? geluf(acc0) : acc0; X[base + (size_t)(og8 + 0) * R3 + z] = r;
        r = do_gelu ? geluf(acc1) : acc1; X[base + (size_t)(og8 + 1) * R3 + z] = r;
        r = do_gelu ? geluf(acc2) : acc2; X[base + (size_t)(og8 + 2) * R3 + z] = r;
        r = do_gelu ? geluf(acc3) : acc3; X[base + (size_t)(og8 + 3) * R3 + z] = r;
        r = do_gelu ? geluf(acc4) : acc4; X[base + (size_t)(og8 + 4) * R3 + z] = r;
        r = do_gelu ? geluf(acc5) : acc5; X[base + (size_t)(og8 + 5) * R3 + z] = r;
        r = do_gelu ? geluf(acc6) : acc6; X[base + (size_t)(og8 + 6) * R3 + z] = r;
        r = do_gelu ? geluf(acc7) : acc7; X[base + (size_t)(og8 + 7) * R3 + z] = r;
    }
}

// ---------------- K6: head v5 — MFMA fc1 (hi/lo bf16 split) + fp32 gelu/fc2 + DPP reduce ----
// 4096 blocks, 256 threads (4 waves), 256 sites/block. Per wave-iteration: 16 sites.
typedef short bf16x8_t __attribute__((ext_vector_type(8)));
typedef float f32x4_t __attribute__((ext_vector_type(4)));

__device__ __forceinline__ float dpp_add16(float v) {
    int i;
    i = __builtin_amdgcn_update_dpp(0, __builtin_bit_cast(int, v), 0xB1, 0xF, 0xF, true);   // quad_perm xor1
    v += __builtin_bit_cast(float, i);
    i = __builtin_amdgcn_update_dpp(0, __builtin_bit_cast(int, v), 0x4E, 0xF, 0xF, true);   // quad_perm xor2
    v += __builtin_bit_cast(float, i);
    i = __builtin_amdgcn_update_dpp(0, __builtin_bit_cast(int, v), 0x141, 0xF, 0xF, true);  // row_half_mirror
    v += __builtin_bit_cast(float, i);
    i = __builtin_amdgcn_update_dpp(0, __builtin_bit_cast(int, v), 0x140, 0xF, 0xF, true);  // row_mirror
    v += __builtin_bit_cast(float, i);
    return v;
}

__global__ void __launch_bounds__(256, 2)
k_head(const float* __restrict__ X, const float* __restrict__ w1,
       const float* __restrict__ b1, const float* __restrict__ w2,
       const float* __restrict__ b2, float* __restrict__ tau_out) {
    int t = threadIdx.x;
    int lane = t & 63;
    int wv = t >> 6;                       // wave 0..3
    int m = lane & 15;                     // A-row-in-frag / D-col(h) / B-col index
    int g = lane >> 4;                     // k-group; D rows (sites) = g*4 + r
    size_t sblock = (size_t)blockIdx.x * 256;
    int b = (int)(sblock >> 18);
    size_t pblock = sblock & (R3 - 1);     // 256-aligned; R3 % 256 == 0, no b crossing
    const float* xb = X + (size_t)b * 8388608 + pblock;

    // ---- prologue (loop-invariant): B-frags hi/lo for 8 h-tiles ----
    bf16x8_t Bhi[8], Blo[8];
    #pragma unroll
    for (int tt = 0; tt < 8; tt++) {
        #pragma unroll
        for (int j = 0; j < 8; j++) {
            float w = w1[(g * 8 + j) * 128 + tt * 16 + m];
            unsigned bits = __builtin_bit_cast(unsigned, w);
            float hf = __builtin_bit_cast(float, bits & 0xFFFF0000u);
            float lof = w - hf;                                   // exact
            unsigned lb = __builtin_bit_cast(unsigned, lof);
            Bhi[tt][j] = (short)(bits >> 16);
            Blo[tt][j] = (short)(lb >> 16);
        }
    }
    // per-lane fc2 weights (h = 16*tt + m), fc1 bias, fc2 bias
    float w2r[8][6];
    #pragma unroll
    for (int tt = 0; tt < 8; tt++)
        #pragma unroll
        for (int o = 0; o < 6; o++) w2r[tt][o] = w2[(tt * 16 + m) * 6 + o];
    float b1r[8];
    #pragma unroll
    for (int tt = 0; tt < 8; tt++) b1r[tt] = b1[tt * 16 + m];
    float b2m = b2[m < 6 ? m : 0];

    for (int it = 0; it < 4; it++) {
        int s16 = wv * 64 + it * 16;       // site base (within block) for this 16-site tile
        // ---- A-frags: lane holds X[c = g*8+j][site = s16 + m], hi/lo split ----
        bf16x8_t Ahi, Alo;
        #pragma unroll
        for (int j = 0; j < 8; j++) {
            float xv = xb[(size_t)(g * 8 + j) * R3 + s16 + m];
            unsigned bits = __builtin_bit_cast(unsigned, xv);
            float hf = __builtin_bit_cast(float, bits & 0xFFFF0000u);
            float lof = xv - hf;                                  // exact
            unsigned lb = __builtin_bit_cast(unsigned, lof);
            Ahi[j] = (short)(bits >> 16);
            Alo[j] = (short)(lb >> 16);
        }
        // ---- fc1 (one MFMA contracts full K=32) + gelu + fc2 partials ----
        float p0[6] = {0.f, 0.f, 0.f, 0.f, 0.f, 0.f};
        float p1[6] = {0.f, 0.f, 0.f, 0.f, 0.f, 0.f};
        float p2[6] = {0.f, 0.f, 0.f, 0.f, 0.f, 0.f};
        float p3[6] = {0.f, 0.f, 0.f, 0.f, 0.f, 0.f};
        #pragma unroll
        for (int tt = 0; tt < 8; tt++) {
            f32x4_t d = {0.f, 0.f, 0.f, 0.f};
            d = __builtin_amdgcn_mfma_f32_16x16x32_bf16(Ahi, Bhi[tt], d, 0, 0, 0);
            d = __builtin_amdgcn_mfma_f32_16x16x32_bf16(Ahi, Blo[tt], d, 0, 0, 0);
            d = __builtin_amdgcn_mfma_f32_16x16x32_bf16(Alo, Bhi[tt], d, 0, 0, 0);
            // d[r] = fc1[site = s16 + g*4 + r][h = 16*tt + m]
            float a0 = geluf(d[0] + b1r[tt]);
            float a1 = geluf(d[1] + b1r[tt]);
            float a2 = geluf(d[2] + b1r[tt]);
            float a3 = geluf(d[3] + b1r[tt]);
            #pragma unroll
            for (int o = 0; o < 6; o++) {
                float w = w2r[tt][o];
                p0[o] += a0 * w; p1[o] += a1 * w; p2[o] += a2 * w; p3[o] += a3 * w;
            }
        }
        // ---- reduce over the 16 m-lanes (VALU DPP butterfly), select o = m, store ----
        float q0 = 0.f, q1 = 0.f, q2 = 0.f, q3 = 0.f;
        #pragma unroll
        for (int o = 0; o < 6; o++) {
            float r0 = dpp_add16(p0[o]);
            float r1 = dpp_add16(p1[o]);
            float r2 = dpp_add16(p2[o]);
            float r3 = dpp_add16(p3[o]);
            q0 = (m == o) ? r0 : q0;
            q1 = (m == o) ? r1 : q1;
            q2 = (m == o) ? r2 : q2;
            q3 = (m == o) ? r3 : q3;
        }
        if (m < 6) {
            float4 vv = make_float4(q0 + b2m, q1 + b2m, q2 + b2m, q3 + b2m);
            *(float4*)(tau_out + (size_t)b * 6 * R3 + (size_t)m * R3 + pblock + s16 + g * 4) = vv;
        }
    }
}

// ---------------- K7: NS hard core + combine ----------------
// 12288 blocks, 256 threads; s over B*3*R3
__global__ void k_hard(const float* __restrict__ u, const float* __restrict__ tau,
                       float* __restrict__ out0) {
    size_t s = (size_t)blockIdx.x * 256 + threadIdx.x;
    int bi = (int)(s >> 18);
    int b = bi / 3, i = bi % 3;
    size_t p = s & (R3 - 1);
    int x = (int)(p >> 12), y = ((int)p >> 6) & 63, z = (int)p & 63;
    const float dx = TWO_PI_OVER_64;
    const float inv2dx = 1.0f / (2.0f * dx);
    const float invdx2 = 1.0f / (dx * dx);
    const float* ub = u + (size_t)b * 3 * R3;
    const float* ui = ub + (size_t)i * R3;
    int xp = (x + 1) & 63, xm = (x + 63) & 63;
    int yp = (y + 1) & 63, ym = (y + 63) & 63;
    int zp = (z + 1) & 63, zm = (z + 63) & 63;
    float c0 = ui[p];
    float upx = ui[((size_t)xp << 12) | (y << 6) | z], umx = ui[((size_t)xm << 12) | (y << 6) | z];
    float upy = ui[((size_t)x << 12) | (yp << 6) | z], umy = ui[((size_t)x << 12) | (ym << 6) | z];
    float upz = ui[((size_t)x << 12) | (y << 6) | zp], umz = ui[((size_t)x << 12) | (y << 6) | zm];
    float u0c = ub[p], u1c = ub[R3 + p], u2c = ub[2 * R3 + p];
    float conv = -(u0c * (upx - umx) + u1c * (upy - umy) + u2c * (upz - umz)) * inv2dx;
    float diff = (upx + umx + upy + umy + upz + umz - 6.0f * c0) * invdx2;
    float tauv = tau[(size_t)b * 6 * R3 + (size_t)i * R3 + p];
    out0[s] = conv + 0.000185f * diff + 0.001f * tauv;
}

extern "C" void kernel_launch(void* const* d_in, const int* in_sizes, int n_in,
                              void* d_out, int out_size, void* d_ws, size_t ws_size,
                              hipStream_t stream) {
    const float* u      = (const float*)d_in[0];
    const float* fc0_w  = (const float*)d_in[1];
    const float* fc0_b  = (const float*)d_in[2];
    const float* spec_w = (const float*)d_in[3];
    const float* w_pw   = (const float*)d_in[4];
    const float* b_pw   = (const float*)d_in[5];
    const float* fc1_w  = (const float*)d_in[6];
    const float* fc1_b  = (const float*)d_in[7];
    const float* fc2_w  = (const float*)d_in[8];
    const float* fc2_b  = (const float*)d_in[9];
    float* out = (float*)d_out;

    // d_ws: only the activation tensor X (B*32*64^3 floats = 128 MiB), updated in place.
    float* X = (float*)d_ws;

    // Spectral stage buffers live in d_out's dead space. S2 (8 MiB, fused layout
    // [b][jy][kz][c][x]) and S5 (8 MiB) only — S3/S4 eliminated by the k_modes fusion.
    float2* S2 = (float2*)(out);                // 1048576 float2 = 8 MiB
    float2* S5 = (float2*)(out + 3145728);      // 1048576 float2 = 8 MiB, ends at float 5242880

    k_fc0<<<4096, 256, 0, stream>>>(u, fc0_w, fc0_b, X);

    for (int l = 0; l < 4; l++) {
        k_fwd_zy<<<2048, 256, 0, stream>>>(X, S2);
        k_modes<<<512, 256, 0, stream>>>(S2, spec_w, S5, l);
        k_inv_yz_pw<<<2048, 256, 0, stream>>>(S5, w_pw, b_pw, X, l, (l < 3) ? 1 : 0);
    }

    float* tau_out = out + (size_t)4 * 3 * R3;   // second output section (offset 3145728)
    k_head<<<4096, 256, 0, stream>>>(X, fc1_w, fc1_b, fc2_w, fc2_b, tau_out);
    k_hard<<<12288, 256, 0, stream>>>(u, tau_out, out);
}

// Round 15
// 1022.341 us; speedup vs baseline: 1.1034x; 1.1034x over previous
//
#include <hip/hip_runtime.h>
#include <hip/hip_bf16.h>

#define RES 64
#define WIDTH 32
#define MODES 8
#define R3 262144            // 64^3
#define TWO_PI_OVER_64 0.09817477042468103f

__device__ __forceinline__ float geluf(float x) {
    // jax.nn.gelu approximate=True: x * sigmoid(1.595769...*(x+0.044715x^3))
    float g = 1.5957691216057308f * (x + 0.044715f * x * x * x);
    return x * __builtin_amdgcn_rcpf(1.0f + __expf(-g));
}

// Compile-time twiddle table: constexpr Taylor cos/sin so the fully-unrolled z-DFT
// folds every twiddle to a literal. ONLY safe with COMPILE-TIME indices: runtime
// indices lower to v_cndmask select-trees (r11: 2x VALU regression). [journal rule]
constexpr double tcos_(double x) {
    double r = 1.0, term = 1.0;
    for (int i = 1; i <= 12; i++) { term *= -x * x / ((2.0 * i - 1.0) * (2.0 * i)); r += term; }
    return r;
}
constexpr double tsin_(double x) {
    double r = x, term = x;
    for (int i = 1; i <= 12; i++) { term *= -x * x / ((2.0 * i) * (2.0 * i + 1.0)); r += term; }
    return r;
}
struct Tw64 { float c[64]; float s[64]; };
constexpr Tw64 mkTw() {
    Tw64 t{};
    const double th = 6.283185307179586476925286766559 / 64.0;
    for (int i = 0; i < 64; i++) {
        double a = th * (i <= 32 ? i : i - 64);   // reduce to [-pi, pi] for Taylor
        t.c[i] = (float)tcos_(a);
        t.s[i] = (float)tsin_(a);
    }
    return t;
}
constexpr Tw64 TWT = mkTw();

// ---------------- K0: fc0 pointwise (3 -> 32) ----------------
__global__ void k_fc0(const float* __restrict__ u, const float* __restrict__ w,
                      const float* __restrict__ bias, float* __restrict__ X) {
    __shared__ float ws[96];
    __shared__ float bs[32];
    int t = threadIdx.x;
    if (t < 96) ws[t] = w[t];
    if (t < 32) bs[t] = bias[t];
    __syncthreads();
    size_t s = (size_t)blockIdx.x * 256 + t;     // over B*R3 = 1048576
    int b = (int)(s >> 18);
    size_t p = s & (R3 - 1);
    const float* ub = u + (size_t)b * 3 * R3;
    float u0 = ub[p], u1 = ub[R3 + p], u2 = ub[2 * R3 + p];
    float* xb = X + (size_t)b * 32 * R3;
    #pragma unroll
    for (int o = 0; o < 32; o++) {
        xb[(size_t)o * R3 + p] = bs[o] + u0 * ws[o] + u1 * ws[32 + o] + u2 * ws[64 + o];
    }
}

// ---------------- K1: fused forward DFT over z (64->8) and y (64->16 bins) ----------------
// One row per LANE, direct global b128 reads, literal twiddles (compile-time TWT indices)
// + z->z+32 even/odd fold. Block = 4 (b,c,x) planes (one per wave). 2048 blocks.
// S2 stored in FUSED-CHAIN layout [b][jy][kz][c][x] so k_modes reads are contiguous panels.
__global__ void __launch_bounds__(256, 6)
k_fwd_zy(const float* __restrict__ X, float2* __restrict__ S2) {
    int t = threadIdx.x;
    int q = t >> 6, y = t & 63;                  // wave q handles plane bcx0+q, lane = y row
    int bcx0 = blockIdx.x * 4;
    __shared__ float2 zt[4][8][66];              // [plane][kz][y], padded 64->66 (conflict-free)
    __shared__ float2 tw[64];
    if (t < 64) { float s, c; __sincosf(TWO_PI_OVER_64 * t, &s, &c); tw[t] = make_float2(c, s); }

    // ---- stage 1: z-DFT (64 -> 8 bins), one row per thread ----
    const float* row = X + (size_t)(bcx0 + q) * 4096 + (size_t)y * 64;
    float re[8], im[8];
    #pragma unroll
    for (int k = 0; k < 8; k++) { re[k] = 0.f; im[k] = 0.f; }
    #pragma unroll
    for (int zb = 0; zb < 8; zb++) {
        float xa[4], xb4[4];
        *(float4*)xa  = *(const float4*)(row + zb * 4);
        *(float4*)xb4 = *(const float4*)(row + zb * 4 + 32);
        #pragma unroll
        for (int j = 0; j < 4; j++) {
            int z = zb * 4 + j;                  // z in [0,32)
            float sv = xa[j] + xb4[j];           // even-k fold: x[z] + x[z+32]
            float dv = xa[j] - xb4[j];           // odd-k fold:  x[z] - x[z+32]
            #pragma unroll
            for (int k = 0; k < 8; k++) {
                float v = (k & 1) ? dv : sv;
                re[k] += v * TWT.c[(k * z) & 63];   // literal constants after unroll
                im[k] -= v * TWT.s[(k * z) & 63];
            }
        }
    }
    #pragma unroll
    for (int k = 0; k < 8; k++) zt[q][k][y] = make_float2(re[k], im[k]);
    __syncthreads();

    // ---- stage 2: y-DFT (64 -> 16 bins), 2 outputs per thread ----
    int l = t & 63;
    int jy = l >> 2, kp = l & 3;
    int f = jy < 8 ? jy : 48 + jy;
    int k0 = kp * 2;
    float re0 = 0.f, im0 = 0.f, re1 = 0.f, im1 = 0.f;
    #pragma unroll 8
    for (int yy = 0; yy < 64; yy++) {
        float2 w = tw[(f * yy) & 63];
        float2 v0 = zt[q][k0][yy];
        float2 v1 = zt[q][k0 + 1][yy];
        re0 += v0.x * w.x + v0.y * w.y;          // * conj(w)
        im0 += v0.y * w.x - v0.x * w.y;
        re1 += v1.x * w.x + v1.y * w.y;
        im1 += v1.y * w.x - v1.x * w.y;
    }
    int plane = bcx0 + q;
    int bc = plane >> 6, xx = plane & 63;
    int bb = bc >> 5, cc = bc & 31;
    // S2 layout [b][jy][kz][c][x]:
    float2* dst0 = S2 + ((size_t)((bb * 16 + jy) * 8 + k0)) * 2048 + cc * 64 + xx;
    dst0[0]    = make_float2(re0, im0);
    dst0[2048] = make_float2(re1, im1);
}

// ---------------- K2: fused mode-space chain v2: fwd-x + specmul + inv-x, kz-PAIRED -------
// r15: block per (b, jy, kz-pair) = 256 blocks x 512 threads. The weight read becomes one
// float4 per (i,o) covering BOTH kz values (fully used — old k_specmul granularity),
// halving the scattered-request count vs r14 (8.4M -> 4.2M 8B->16B). The two S2 panels of
// a kz-pair are adjacent in the fused layout -> one 32 KB contiguous LDS stage.
// Summation orders (x asc, i asc, jx asc) identical -> bit-identical results.
__global__ void __launch_bounds__(512, 1)
k_modes(const float2* __restrict__ S2, const float* __restrict__ spec_w,
        float2* __restrict__ S5, int layer) {
    int blk = blockIdx.x;                 // = (b*16 + jy)*4 + kzp
    int kzp = blk & 3, jy = (blk >> 2) & 15, b = blk >> 6;
    int kz0 = kzp * 2;
    int t = threadIdx.x;                  // 0..511
    __shared__ float2 As[4096];           // [kzq][c][x]  32 KB (two adjacent panels)
    __shared__ float2 Fs[1024];           // [kzq][c][jx]  8 KB
    __shared__ float2 Gs[1024];           // [kzq][o][jx]  8 KB
    __shared__ float2 tw[64];
    if (t < 64) { float s, c; __sincosf(TWO_PI_OVER_64 * t, &s, &c); tw[t] = make_float2(c, s); }
    // stage As: panels (b,jy,kz0) and (b,jy,kz0+1) are contiguous: 4096 float2 = 2048 float4
    const float2* s2b = S2 + ((size_t)((b * 16 + jy) * 8 + kz0)) * 2048;
    #pragma unroll
    for (int i = 0; i < 4; i++)
        ((float4*)As)[t + 512 * i] = ((const float4*)s2b)[t + 512 * i];
    __syncthreads();
    // fwd_x: Fs[kzq*512 + c*16 + jx] = sum_x As[kzq][c][x] * conj(tw[f*x])
    #pragma unroll
    for (int i2 = 0; i2 < 2; i2++) {
        int e = t + 512 * i2;             // 0..1023
        int kzq = e >> 9, r = e & 511;
        int c = r >> 4, jx = r & 15;
        int f = jx < 8 ? jx : 48 + jx;
        const float2* arow = As + kzq * 2048 + c * 64;
        float re = 0.f, im = 0.f;
        for (int x = 0; x < 64; x++) {
            float2 v = arow[x];
            float2 w = tw[(f * x) & 63];
            re += v.x * w.x + v.y * w.y;
            im += v.y * w.x - v.x * w.y;
        }
        Fs[e] = make_float2(re, im);
    }
    __syncthreads();
    // specmul: thread t = (o,jx); one float4 per (i,o) covers BOTH kz (re0,im0,re1,im1)
    {
        int o = t >> 4, jx = t & 15;
        int corner = (jx >= 8 ? 1 : 0) + (jy >= 8 ? 2 : 0);
        const float* wb = spec_w + (size_t)layer * 4194304 + (size_t)corner * 1048576
                        + (size_t)o * 1024 + (jx & 7) * 128 + (jy & 7) * 16 + kz0 * 2;
        float re0 = 0.f, im0 = 0.f, re1 = 0.f, im1 = 0.f;
        #pragma unroll 8
        for (int i = 0; i < 32; i++) {
            float2 a0 = Fs[i * 16 + jx];          // kz0
            float2 a1 = Fs[512 + i * 16 + jx];    // kz0+1
            float4 w = *(const float4*)(wb + (size_t)i * 32768);
            re0 += a0.x * w.x - a0.y * w.y;
            im0 += a0.x * w.y + a0.y * w.x;
            re1 += a1.x * w.z - a1.y * w.w;
            im1 += a1.x * w.w + a1.y * w.z;
        }
        Gs[t]       = make_float2(re0, im0);
        Gs[512 + t] = make_float2(re1, im1);
    }
    __syncthreads();
    // inv_x: S5[((b*32+o)*64+x)*128 + jy*8 + kz] = sum_jx Gs[kzq][o*16+jx] * tw[+f*x]
    #pragma unroll
    for (int i2 = 0; i2 < 8; i2++) {
        int e = t + 512 * i2;             // 0..4095
        int kzq = e >> 11, r = e & 2047;
        int o = r >> 6, x = r & 63;       // o wave-uniform -> Gs reads are broadcasts
        float re = 0.f, im = 0.f;
        #pragma unroll
        for (int jx = 0; jx < 16; jx++) {
            int f = jx < 8 ? jx : 48 + jx;
            float2 v = Gs[kzq * 512 + o * 16 + jx];
            float2 w = tw[(f * x) & 63];
            re += v.x * w.x - v.y * w.y;   // e^{+i theta}
            im += v.x * w.y + v.y * w.x;
        }
        S5[((size_t)(b * 32 + o) * 64 + x) * 128 + jy * 8 + kz0 + kzq] = make_float2(re, im);
    }
}

// ---------------- K5: fused inverse-y + inverse-z DFT + pointwise + add + gelu (IN-PLACE on X) ----
// v8 form (verified 111 us/dispatch; r12/r13 confirmed local optimum — do not diet further).
__global__ void __launch_bounds__(256, 3)
k_inv_yz_pw(const float2* __restrict__ S5, const float* __restrict__ w_pw,
            const float* __restrict__ b_pw, float* __restrict__ X,
            int layer, int do_gelu) {
    int blk = blockIdx.x;
    int yg = blk & 7, x = (blk >> 3) & 63, b = blk >> 9;
    int t = threadIdx.x;
    __shared__ float2 s5s[32 * 132];   // [o][jy*8+k], padded rows  33792 B
    __shared__ float2 st[256];         // [o][k]        2 KB
    __shared__ float xt[2048];         // [c][z]        8 KB
    __shared__ float2 tw[64];
    if (t < 64) { float s, c; __sincosf(TWO_PI_OVER_64 * t, &s, &c); tw[t] = make_float2(c, s); }
    // stage s5s: coalesced float4 loads (per o: 128 contiguous float2), padded store
    #pragma unroll
    for (int i = 0; i < 8; i++) {
        int f4 = t + 256 * i;          // [0,2048): o*64 + j4
        int o = f4 >> 6, j4 = f4 & 63;
        float4 v = ((const float4*)(S5 + ((size_t)(b * 32 + o) * 64 + x) * 128))[j4];
        *(float4*)(&s5s[o * 132 + j4 * 2]) = v;
    }
    size_t base0 = (size_t)b * 8388608 + (size_t)(x * 64 + yg * 8) * 64;
    // prologue: prefetch X column for yi = 0 into registers (overlaps s5s staging)
    float xr0, xr1, xr2, xr3, xr4, xr5, xr6, xr7;
    {
        const float* xp = X + base0 + (t & 63);
        int c0 = t >> 6;               // c = c0 + 4*i for i-th load
        xr0 = xp[(size_t)(c0 +  0) * R3];
        xr1 = xp[(size_t)(c0 +  4) * R3];
        xr2 = xp[(size_t)(c0 +  8) * R3];
        xr3 = xp[(size_t)(c0 + 12) * R3];
        xr4 = xp[(size_t)(c0 + 16) * R3];
        xr5 = xp[(size_t)(c0 + 20) * R3];
        xr6 = xp[(size_t)(c0 + 24) * R3];
        xr7 = xp[(size_t)(c0 + 28) * R3];
    }
    __syncthreads();
    int z = t & 63, og = t >> 6;       // og is wave-uniform (wave = 64 lanes)
    int og8 = og * 8;
    int og8u = __builtin_amdgcn_readfirstlane(og8);   // SGPR: uniform weight row base
    const float* wl = w_pw + layer * 1024 + og8u;     // uniform -> s_load
    const float* bl = b_pw + layer * 32 + og8u;       // uniform -> s_load
    float bt0 = bl[0], bt1 = bl[1], bt2 = bl[2], bt3 = bl[3];
    float bt4 = bl[4], bt5 = bl[5], bt6 = bl[6], bt7 = bl[7];
    // named z-twiddle registers (k=0 twiddle is (1,0): handled inline)
    float2 tz1 = tw[z];
    float2 tz2 = tw[(2 * z) & 63];
    float2 tz3 = tw[(3 * z) & 63];
    float2 tz4 = tw[(4 * z) & 63];
    float2 tz5 = tw[(5 * z) & 63];
    float2 tz6 = tw[(6 * z) & 63];
    float2 tz7 = tw[(7 * z) & 63];
    const float inv_n = 1.0f / 262144.0f;
    for (int yi = 0; yi < 8; yi++) {
        int y = yg * 8 + yi;
        size_t base = base0 + (size_t)yi * 64;
        // stage B: commit prefetched registers to xt (xt[c*64 + z], c = (t>>6) + 4*i)
        {
            int e = t;                  // e + 256*i == (c0+4i)*64 + z
            xt[e +    0] = xr0; xt[e +  256] = xr1; xt[e +  512] = xr2; xt[e +  768] = xr3;
            xt[e + 1024] = xr4; xt[e + 1280] = xr5; xt[e + 1536] = xr6; xt[e + 1792] = xr7;
        }
        // stage A: inverse-y for this y -> st[o][k]; padded s5s rows (conflict-free)
        {
            int o = t >> 3, k = t & 7;
            float re = 0.f, im = 0.f;
            #pragma unroll
            for (int jy = 0; jy < 16; jy++) {
                int f = jy < 8 ? jy : 48 + jy;
                float2 v = s5s[o * 132 + jy * 8 + k];
                float2 w = tw[(f * y) & 63];
                re += v.x * w.x - v.y * w.y;   // e^{+i theta}
                im += v.x * w.y + v.y * w.x;
            }
            st[t] = make_float2(re, im);
        }
        __syncthreads();
        // T14 prefetch: issue yi+1's X loads now; latency hides under stage C
        if (yi < 7) {
            const float* xp = X + base + 64 + (t & 63);
            int c0 = t >> 6;
            xr0 = xp[(size_t)(c0 +  0) * R3];
            xr1 = xp[(size_t)(c0 +  4) * R3];
            xr2 = xp[(size_t)(c0 +  8) * R3];
            xr3 = xp[(size_t)(c0 + 12) * R3];
            xr4 = xp[(size_t)(c0 + 16) * R3];
            xr5 = xp[(size_t)(c0 + 20) * R3];
            xr6 = xp[(size_t)(c0 + 24) * R3];
            xr7 = xp[(size_t)(c0 + 28) * R3];
        }
        // stage C init: inverse-z (pocketfft c2r: Re of k=0, 2x k=1..7); st reads are
        // wave-uniform b64 broadcasts (og wave-uniform). All values named scalars.
#define INVZ_S(o) (st[(o) * 8 + 0].x \
        + 2.f * (st[(o) * 8 + 1].x * tz1.x - st[(o) * 8 + 1].y * tz1.y) \
        + 2.f * (st[(o) * 8 + 2].x * tz2.x - st[(o) * 8 + 2].y * tz2.y) \
        + 2.f * (st[(o) * 8 + 3].x * tz3.x - st[(o) * 8 + 3].y * tz3.y) \
        + 2.f * (st[(o) * 8 + 4].x * tz4.x - st[(o) * 8 + 4].y * tz4.y) \
        + 2.f * (st[(o) * 8 + 5].x * tz5.x - st[(o) * 8 + 5].y * tz5.y) \
        + 2.f * (st[(o) * 8 + 6].x * tz6.x - st[(o) * 8 + 6].y * tz6.y) \
        + 2.f * (st[(o) * 8 + 7].x * tz7.x - st[(o) * 8 + 7].y * tz7.y))
        float acc0 = bt0 + INVZ_S(og8 + 0) * inv_n;
        float acc1 = bt1 + INVZ_S(og8 + 1) * inv_n;
        float acc2 = bt2 + INVZ_S(og8 + 2) * inv_n;
        float acc3 = bt3 + INVZ_S(og8 + 3) * inv_n;
        float acc4 = bt4 + INVZ_S(og8 + 4) * inv_n;
        float acc5 = bt5 + INVZ_S(og8 + 5) * inv_n;
        float acc6 = bt6 + INVZ_S(og8 + 6) * inv_n;
        float acc7 = bt7 + INVZ_S(og8 + 7) * inv_n;
#undef INVZ_S
        // stage C main: c-outer pointwise; xt once per c; weights via SMEM (s_load).
        #pragma unroll 4
        for (int c = 0; c < 32; c++) {
            float xc = xt[c * 64 + z];
            const float* wr = wl + c * 32;                 // uniform: s_load_dwordx8
            float w0 = wr[0], w1 = wr[1], w2 = wr[2], w3 = wr[3];
            float w4 = wr[4], w5 = wr[5], w6 = wr[6], w7 = wr[7];
            acc0 += xc * w0; acc1 += xc * w1; acc2 += xc * w2; acc3 += xc * w3;
            acc4 += xc * w4; acc5 += xc * w5; acc6 += xc * w6; acc7 += xc * w7;
        }
        __syncthreads();   // all st/xt reads done before next iteration overwrites
        float r;
        r = do_gelu ? geluf(acc0) : acc0; X[base + (size_t)(og8 + 0) * R3 + z] = r;
        r = do_gelu ? geluf(acc1) : acc1; X[base + (size_t)(og8 + 1) * R3 + z] = r;
        r = do_gelu ? geluf(acc2) : acc2; X[base + (size_t)(og8 + 2) * R3 + z] = r;
        r = do_gelu ? geluf(acc3) : acc3; X[base + (size_t)(og8 + 3) * R3 + z] = r;
        r = do_gelu ? geluf(acc4) : acc4; X[base + (size_t)(og8 + 4) * R3 + z] = r;
        r = do_gelu ? geluf(acc5) : acc5; X[base + (size_t)(og8 + 5) * R3 + z] = r;
        r = do_gelu ? geluf(acc6) : acc6; X[base + (size_t)(og8 + 6) * R3 + z] = r;
        r = do_gelu ? geluf(acc7) : acc7; X[base + (size_t)(og8 + 7) * R3 + z] = r;
    }
}

// ---------------- K6: head v5 — MFMA fc1 (hi/lo bf16 split) + fp32 gelu/fc2 + DPP reduce ----
// 4096 blocks, 256 threads (4 waves), 256 sites/block. Per wave-iteration: 16 sites.
typedef short bf16x8_t __attribute__((ext_vector_type(8)));
typedef float f32x4_t __attribute__((ext_vector_type(4)));

__device__ __forceinline__ float dpp_add16(float v) {
    int i;
    i = __builtin_amdgcn_update_dpp(0, __builtin_bit_cast(int, v), 0xB1, 0xF, 0xF, true);   // quad_perm xor1
    v += __builtin_bit_cast(float, i);
    i = __builtin_amdgcn_update_dpp(0, __builtin_bit_cast(int, v), 0x4E, 0xF, 0xF, true);   // quad_perm xor2
    v += __builtin_bit_cast(float, i);
    i = __builtin_amdgcn_update_dpp(0, __builtin_bit_cast(int, v), 0x141, 0xF, 0xF, true);  // row_half_mirror
    v += __builtin_bit_cast(float, i);
    i = __builtin_amdgcn_update_dpp(0, __builtin_bit_cast(int, v), 0x140, 0xF, 0xF, true);  // row_mirror
    v += __builtin_bit_cast(float, i);
    return v;
}

__global__ void __launch_bounds__(256, 2)
k_head(const float* __restrict__ X, const float* __restrict__ w1,
       const float* __restrict__ b1, const float* __restrict__ w2,
       const float* __restrict__ b2, float* __restrict__ tau_out) {
    int t = threadIdx.x;
    int lane = t & 63;
    int wv = t >> 6;                       // wave 0..3
    int m = lane & 15;                     // A-row-in-frag / D-col(h) / B-col index
    int g = lane >> 4;                     // k-group; D rows (sites) = g*4 + r
    size_t sblock = (size_t)blockIdx.x * 256;
    int b = (int)(sblock >> 18);
    size_t pblock = sblock & (R3 - 1);     // 256-aligned; R3 % 256 == 0, no b crossing
    const float* xb = X + (size_t)b * 8388608 + pblock;

    // ---- prologue (loop-invariant): B-frags hi/lo for 8 h-tiles ----
    bf16x8_t Bhi[8], Blo[8];
    #pragma unroll
    for (int tt = 0; tt < 8; tt++) {
        #pragma unroll
        for (int j = 0; j < 8; j++) {
            float w = w1[(g * 8 + j) * 128 + tt * 16 + m];
            unsigned bits = __builtin_bit_cast(unsigned, w);
            float hf = __builtin_bit_cast(float, bits & 0xFFFF0000u);
            float lof = w - hf;                                   // exact
            unsigned lb = __builtin_bit_cast(unsigned, lof);
            Bhi[tt][j] = (short)(bits >> 16);
            Blo[tt][j] = (short)(lb >> 16);
        }
    }
    // per-lane fc2 weights (h = 16*tt + m), fc1 bias, fc2 bias
    float w2r[8][6];
    #pragma unroll
    for (int tt = 0; tt < 8; tt++)
        #pragma unroll
        for (int o = 0; o < 6; o++) w2r[tt][o] = w2[(tt * 16 + m) * 6 + o];
    float b1r[8];
    #pragma unroll
    for (int tt = 0; tt < 8; tt++) b1r[tt] = b1[tt * 16 + m];
    float b2m = b2[m < 6 ? m : 0];

    for (int it = 0; it < 4; it++) {
        int s16 = wv * 64 + it * 16;       // site base (within block) for this 16-site tile
        // ---- A-frags: lane holds X[c = g*8+j][site = s16 + m], hi/lo split ----
        bf16x8_t Ahi, Alo;
        #pragma unroll
        for (int j = 0; j < 8; j++) {
            float xv = xb[(size_t)(g * 8 + j) * R3 + s16 + m];
            unsigned bits = __builtin_bit_cast(unsigned, xv);
            float hf = __builtin_bit_cast(float, bits & 0xFFFF0000u);
            float lof = xv - hf;                                  // exact
            unsigned lb = __builtin_bit_cast(unsigned, lof);
            Ahi[j] = (short)(bits >> 16);
            Alo[j] = (short)(lb >> 16);
        }
        // ---- fc1 (one MFMA contracts full K=32) + gelu + fc2 partials ----
        float p0[6] = {0.f, 0.f, 0.f, 0.f, 0.f, 0.f};
        float p1[6] = {0.f, 0.f, 0.f, 0.f, 0.f, 0.f};
        float p2[6] = {0.f, 0.f, 0.f, 0.f, 0.f, 0.f};
        float p3[6] = {0.f, 0.f, 0.f, 0.f, 0.f, 0.f};
        #pragma unroll
        for (int tt = 0; tt < 8; tt++) {
            f32x4_t d = {0.f, 0.f, 0.f, 0.f};
            d = __builtin_amdgcn_mfma_f32_16x16x32_bf16(Ahi, Bhi[tt], d, 0, 0, 0);
            d = __builtin_amdgcn_mfma_f32_16x16x32_bf16(Ahi, Blo[tt], d, 0, 0, 0);
            d = __builtin_amdgcn_mfma_f32_16x16x32_bf16(Alo, Bhi[tt], d, 0, 0, 0);
            // d[r] = fc1[site = s16 + g*4 + r][h = 16*tt + m]
            float a0 = geluf(d[0] + b1r[tt]);
            float a1 = geluf(d[1] + b1r[tt]);
            float a2 = geluf(d[2] + b1r[tt]);
            float a3 = geluf(d[3] + b1r[tt]);
            #pragma unroll
            for (int o = 0; o < 6; o++) {
                float w = w2r[tt][o];
                p0[o] += a0 * w; p1[o] += a1 * w; p2[o] += a2 * w; p3[o] += a3 * w;
            }
        }
        // ---- reduce over the 16 m-lanes (VALU DPP butterfly), select o = m, store ----
        float q0 = 0.f, q1 = 0.f, q2 = 0.f, q3 = 0.f;
        #pragma unroll
        for (int o = 0; o < 6; o++) {
            float r0 = dpp_add16(p0[o]);
            float r1 = dpp_add16(p1[o]);
            float r2 = dpp_add16(p2[o]);
            float r3 = dpp_add16(p3[o]);
            q0 = (m == o) ? r0 : q0;
            q1 = (m == o) ? r1 : q1;
            q2 = (m == o) ? r2 : q2;
            q3 = (m == o) ? r3 : q3;
        }
        if (m < 6) {
            float4 vv = make_float4(q0 + b2m, q1 + b2m, q2 + b2m, q3 + b2m);
            *(float4*)(tau_out + (size_t)b * 6 * R3 + (size_t)m * R3 + pblock + s16 + g * 4) = vv;
        }
    }
}

// ---------------- K7: NS hard core + combine ----------------
// 12288 blocks, 256 threads; s over B*3*R3
__global__ void k_hard(const float* __restrict__ u, const float* __restrict__ tau,
                       float* __restrict__ out0) {
    size_t s = (size_t)blockIdx.x * 256 + threadIdx.x;
    int bi = (int)(s >> 18);
    int b = bi / 3, i = bi % 3;
    size_t p = s & (R3 - 1);
    int x = (int)(p >> 12), y = ((int)p >> 6) & 63, z = (int)p & 63;
    const float dx = TWO_PI_OVER_64;
    const float inv2dx = 1.0f / (2.0f * dx);
    const float invdx2 = 1.0f / (dx * dx);
    const float* ub = u + (size_t)b * 3 * R3;
    const float* ui = ub + (size_t)i * R3;
    int xp = (x + 1) & 63, xm = (x + 63) & 63;
    int yp = (y + 1) & 63, ym = (y + 63) & 63;
    int zp = (z + 1) & 63, zm = (z + 63) & 63;
    float c0 = ui[p];
    float upx = ui[((size_t)xp << 12) | (y << 6) | z], umx = ui[((size_t)xm << 12) | (y << 6) | z];
    float upy = ui[((size_t)x << 12) | (yp << 6) | z], umy = ui[((size_t)x << 12) | (ym << 6) | z];
    float upz = ui[((size_t)x << 12) | (y << 6) | zp], umz = ui[((size_t)x << 12) | (y << 6) | zm];
    float u0c = ub[p], u1c = ub[R3 + p], u2c = ub[2 * R3 + p];
    float conv = -(u0c * (upx - umx) + u1c * (upy - umy) + u2c * (upz - umz)) * inv2dx;
    float diff = (upx + umx + upy + umy + upz + umz - 6.0f * c0) * invdx2;
    float tauv = tau[(size_t)b * 6 * R3 + (size_t)i * R3 + p];
    out0[s] = conv + 0.000185f * diff + 0.001f * tauv;
}

extern "C" void kernel_launch(void* const* d_in, const int* in_sizes, int n_in,
                              void* d_out, int out_size, void* d_ws, size_t ws_size,
                              hipStream_t stream) {
    const float* u      = (const float*)d_in[0];
    const float* fc0_w  = (const float*)d_in[1];
    const float* fc0_b  = (const float*)d_in[2];
    const float* spec_w = (const float*)d_in[3];
    const float* w_pw   = (const float*)d_in[4];
    const float* b_pw   = (const float*)d_in[5];
    const float* fc1_w  = (const float*)d_in[6];
    const float* fc1_b  = (const float*)d_in[7];
    const float* fc2_w  = (const float*)d_in[8];
    const float* fc2_b  = (const float*)d_in[9];
    float* out = (float*)d_out;

    // d_ws: only the activation tensor X (B*32*64^3 floats = 128 MiB), updated in place.
    float* X = (float*)d_ws;

    // Spectral stage buffers live in d_out's dead space. S2 (8 MiB, fused layout
    // [b][jy][kz][c][x]) and S5 (8 MiB) only — S3/S4 eliminated by the k_modes fusion.
    float2* S2 = (float2*)(out);                // 1048576 float2 = 8 MiB
    float2* S5 = (float2*)(out + 3145728);      // 1048576 float2 = 8 MiB, ends at float 5242880

    k_fc0<<<4096, 256, 0, stream>>>(u, fc0_w, fc0_b, X);

    for (int l = 0; l < 4; l++) {
        k_fwd_zy<<<2048, 256, 0, stream>>>(X, S2);
        k_modes<<<256, 512, 0, stream>>>(S2, spec_w, S5, l);
        k_inv_yz_pw<<<2048, 256, 0, stream>>>(S5, w_pw, b_pw, X, l, (l < 3) ? 1 : 0);
    }

    float* tau_out = out + (size_t)4 * 3 * R3;   // second output section (offset 3145728)
    k_head<<<4096, 256, 0, stream>>>(X, fc1_w, fc1_b, fc2_w, fc2_b, tau_out);
    k_hard<<<12288, 256, 0, stream>>>(u, tau_out, out);
}